// Round 7
// baseline (320.267 us; speedup 1.0000x reference)
//
#include <hip/hip_runtime.h>

// Problem constants (from reference)
#define BATCH 16384
#define CNUM  8
#define DIN   256
#define NH0   512
#define NH1   256

#define BT       64            // batch rows per block (fallback kernel)
#define BTM      32            // batch rows per block (main kernel)
#define NTMAIN   256           // 4 waves -> 4 blocks/CU = 4 phase groups/SIMD
#define NTHREADS 512           // fallback

#define X_ELEMS  (BATCH * DIN)        // 4194304
#define W0_ELEMS (CNUM * NH0 * DIN)   // 1048576
#define W1_ELEMS (CNUM * NH1 * NH0)   // 1048576
#define WS_NEED  ((size_t)(X_ELEMS + W0_ELEMS + W1_ELEMS) * 2)  // 12.6 MB bf16

typedef __bf16 bf16x8 __attribute__((ext_vector_type(8)));
typedef __bf16 bf16x4 __attribute__((ext_vector_type(4)));
typedef float  f32x4  __attribute__((ext_vector_type(4)));
typedef float  f32x8  __attribute__((ext_vector_type(8)));

#define MFMA16(a, b, c) __builtin_amdgcn_mfma_f32_16x16x32_bf16((a), (b), (c), 0, 0, 0)

// ---------------------------------------------------------------------------
// Prep: fp32 -> bf16 for x, W0, W1 into ws.  786432 chunks x 8 elems.
// ---------------------------------------------------------------------------
__global__ __launch_bounds__(256)
void cvt_bf16(const float* __restrict__ x, const float* __restrict__ W0,
              const float* __restrict__ W1, __bf16* __restrict__ ws) {
    const int i = blockIdx.x * 256 + threadIdx.x;   // chunk of 8 elems
    const float* src;
    __bf16* dst;
    int off;
    if (i < X_ELEMS / 8)                 { src = x;  dst = ws;                        off = i * 8; }
    else if (i < (X_ELEMS + W0_ELEMS)/8) { src = W0; dst = ws + X_ELEMS;             off = (i - X_ELEMS/8) * 8; }
    else                                 { src = W1; dst = ws + X_ELEMS + W0_ELEMS;  off = (i - (X_ELEMS + W0_ELEMS)/8) * 8; }
    f32x8 v = *(const f32x8*)(src + off);
    bf16x8 r;
    #pragma unroll
    for (int j = 0; j < 8; ++j) r[j] = (__bf16)v[j];
    *(bf16x8*)(dst + off) = r;
}

// ---------------------------------------------------------------------------
// Main fused kernel (bf16, 16x16x32 MFMA), BTM=32 rows, 256 threads (4 waves).
// grid = (BATCH/BTM)*CNUM = 4096; c = blockIdx&7 (XCD round-robin).
//
// Design point (round 0-6 evidence): per-wave ILP is compiler-capped
// (VGPR pinned <=64, loads sunk just-in-time); occupancy of same-phase waves
// doesn't help (r3). The untested lever is INDEPENDENT PHASE GROUPS per
// SIMD: LDS 33 KB -> 4 resident blocks/CU, each SIMD hosts 4 waves from 4
// DIFFERENT blocks at full 128-VGPR budget. When one block's waves stall on
// their W-load round-trip, the other three compute.
//
// LDS h0s = 32 granules x 512 elems (1 KB), granule g = kw*2 + bt
//   (kw = n>>5, bt = m>>4). Frag-major: layer-1 ds_read_b128 is
//   lane-contiguous -> conflict-free. xs aliases granules 16..31 during L0.
// Per wave: n-slice 128 (2 halves x 4 at, acc 32 regs), o-slice 64 (4 ot).
// ---------------------------------------------------------------------------
__global__ __launch_bounds__(NTMAIN, 4)
void confounder_main(const __bf16* __restrict__ ws,
                     const float* __restrict__ b0,
                     const float* __restrict__ b1,
                     const float* __restrict__ W2,
                     const float* __restrict__ b2,
                     float* __restrict__ out) {
    __shared__ __align__(16) __bf16 h0s[BTM * NH0];  // 32 KB granule-major
    __shared__ float red[4][BTM];                    // 512 B
    __bf16* xs = h0s + 16 * 512;                     // upper 16 KB alias for x tile

    const __bf16* xbf = ws;
    const __bf16* w0b = ws + X_ELEMS;
    const __bf16* w1b = ws + X_ELEMS + W0_ELEMS;

    const int c    = blockIdx.x & 7;
    const int mb   = blockIdx.x >> 3;
    const int row0 = mb * BTM;

    const int tid  = threadIdx.x;
    const int w    = tid >> 6;    // wave 0..3
    const int lane = tid & 63;
    const int l15  = lane & 15;
    const int l4   = lane >> 4;   // 0..3

    // ---- stage x tile into LDS (granules 16..31), frag-major --------------
    // granule p = mt*8+ks; lane's 8 elems: row mt*16+l15, cols ks*32+8*l4..+7
    #pragma unroll
    for (int q = 0; q < 4; ++q) {
        const int p  = w * 4 + q;             // 0..15
        const int mt = p >> 3, ks = p & 7;
        bf16x8 v = *(const bf16x8*)(xbf + (size_t)(row0 + mt * 16 + l15) * DIN + ks * 32 + 8 * l4);
        *(bf16x8*)(xs + (p * 64 + lane) * 8) = v;
    }

    // W0 rows: half h covers n = h*256 + w*64 + at*16 + l15 (at 0..3)
    const __bf16* w0r  = w0b + ((size_t)c * NH0 + w * 64 + l15) * DIN + 8 * l4;
    const __bf16* w0r1 = w0r + 256 * DIN;

    // prefetch half-0 ks=0 fragments (ride through the barrier)
    bf16x8 a[4];
    #pragma unroll
    for (int at = 0; at < 4; ++at)
        a[at] = *(const bf16x8*)(w0r + at * 16 * DIN);
    __syncthreads();

    f32x4 acc[4][2];   // [at][bt] — 32 regs

    // ================= Layer 0, half h = 0 (n in [0,256)) ==================
    #pragma unroll
    for (int at = 0; at < 4; ++at)
        #pragma unroll
        for (int bt = 0; bt < 2; ++bt)
            acc[at][bt] = (f32x4){0.f, 0.f, 0.f, 0.f};

    #pragma unroll
    for (int ks = 0; ks < 8; ++ks) {
        bf16x8 na[4];
        #pragma unroll
        for (int at = 0; at < 4; ++at)
            na[at] = a[at];
        if (ks < 7) {
            #pragma unroll
            for (int at = 0; at < 4; ++at)
                na[at] = *(const bf16x8*)(w0r + at * 16 * DIN + (ks + 1) * 32);
        }
        bf16x8 bA = *(const bf16x8*)(xs + ((0 * 8 + ks) * 64 + lane) * 8);
        bf16x8 bB = *(const bf16x8*)(xs + ((1 * 8 + ks) * 64 + lane) * 8);
        __builtin_amdgcn_s_setprio(1);
        #pragma unroll
        for (int at = 0; at < 4; ++at) {
            acc[at][0] = MFMA16(a[at], bA, acc[at][0]);
            acc[at][1] = MFMA16(a[at], bB, acc[at][1]);
        }
        __builtin_amdgcn_s_setprio(0);
        #pragma unroll
        for (int at = 0; at < 4; ++at)
            a[at] = na[at];
    }

    // prefetch half-1 ks=0 while epilogue-0 runs
    bf16x8 p4[4];
    #pragma unroll
    for (int at = 0; at < 4; ++at)
        p4[at] = *(const bf16x8*)(w0r1 + at * 16 * DIN);

    // epilogue half 0 -> granules g = (w*2 + (at>>1))*2 + bt (0..15); xs safe
    #pragma unroll
    for (int at = 0; at < 4; ++at) {
        const int nb = w * 64 + at * 16 + 4 * l4;
        const f32x4 b4 = *(const f32x4*)(b0 + c * NH0 + nb);
        const int sub = ((at & 1) * 2 + (l4 >> 1)) * 128 + l15 * 8 + 4 * (l4 & 1);
        #pragma unroll
        for (int bt = 0; bt < 2; ++bt) {
            const int g = (w * 2 + (at >> 1)) * 2 + bt;
            bf16x4 pk;
            #pragma unroll
            for (int r = 0; r < 4; ++r) {
                float v = acc[at][bt][r] + b4[r];
                v = v > 0.f ? v : 0.f;
                pk[r] = (__bf16)v;
            }
            *(bf16x4*)(&h0s[g * 512 + sub]) = pk;
        }
    }

    // ================= Layer 0, half h = 1 (n in [256,512)) ================
    #pragma unroll
    for (int at = 0; at < 4; ++at) {
        a[at] = p4[at];
        #pragma unroll
        for (int bt = 0; bt < 2; ++bt)
            acc[at][bt] = (f32x4){0.f, 0.f, 0.f, 0.f};
    }

    #pragma unroll
    for (int ks = 0; ks < 8; ++ks) {
        bf16x8 na[4];
        #pragma unroll
        for (int at = 0; at < 4; ++at)
            na[at] = a[at];
        if (ks < 7) {
            #pragma unroll
            for (int at = 0; at < 4; ++at)
                na[at] = *(const bf16x8*)(w0r1 + at * 16 * DIN + (ks + 1) * 32);
        }
        bf16x8 bA = *(const bf16x8*)(xs + ((0 * 8 + ks) * 64 + lane) * 8);
        bf16x8 bB = *(const bf16x8*)(xs + ((1 * 8 + ks) * 64 + lane) * 8);
        __builtin_amdgcn_s_setprio(1);
        #pragma unroll
        for (int at = 0; at < 4; ++at) {
            acc[at][0] = MFMA16(a[at], bA, acc[at][0]);
            acc[at][1] = MFMA16(a[at], bB, acc[at][1]);
        }
        __builtin_amdgcn_s_setprio(0);
        #pragma unroll
        for (int at = 0; at < 4; ++at)
            a[at] = na[at];
    }

    // prefetch W1 ks=0 (rides through both barriers below)
    const __bf16* w1r = w1b + ((size_t)c * NH1 + w * 64 + l15) * NH0 + 8 * l4;
    bf16x8 q4[4];
    #pragma unroll
    for (int ot = 0; ot < 4; ++ot)
        q4[ot] = *(const bf16x8*)(w1r + ot * 16 * NH0);

    __syncthreads();   // all waves done reading xs before granules 16..31 write

    // epilogue half 1 -> granules g = 16 + (w*2 + (at>>1))*2 + bt
    #pragma unroll
    for (int at = 0; at < 4; ++at) {
        const int nb = 256 + w * 64 + at * 16 + 4 * l4;
        const f32x4 b4 = *(const f32x4*)(b0 + c * NH0 + nb);
        const int sub = ((at & 1) * 2 + (l4 >> 1)) * 128 + l15 * 8 + 4 * (l4 & 1);
        #pragma unroll
        for (int bt = 0; bt < 2; ++bt) {
            const int g = 16 + (w * 2 + (at >> 1)) * 2 + bt;
            bf16x4 pk;
            #pragma unroll
            for (int r = 0; r < 4; ++r) {
                float v = acc[at][bt][r] + b4[r];
                v = v > 0.f ? v : 0.f;
                pk[r] = (__bf16)v;
            }
            *(bf16x4*)(&h0s[g * 512 + sub]) = pk;
        }
    }
    __syncthreads();   // h0 complete

    // ================= Layer 1 (A=W1 rows o=w*64..+63, B=h0 granules) ======
    f32x4 acc1[4][2];   // [ot][nt] — 32 regs
    #pragma unroll
    for (int ot = 0; ot < 4; ++ot)
        #pragma unroll
        for (int nt = 0; nt < 2; ++nt)
            acc1[ot][nt] = (f32x4){0.f, 0.f, 0.f, 0.f};

    #pragma unroll
    for (int ot = 0; ot < 4; ++ot)
        a[ot] = q4[ot];

    #pragma unroll
    for (int ks = 0; ks < 16; ++ks) {          // granule g = ks*2 + nt
        bf16x8 na[4];
        #pragma unroll
        for (int ot = 0; ot < 4; ++ot)
            na[ot] = a[ot];
        if (ks < 15) {
            #pragma unroll
            for (int ot = 0; ot < 4; ++ot)
                na[ot] = *(const bf16x8*)(w1r + ot * 16 * NH0 + (ks + 1) * 32);
        }
        bf16x8 bA = *(const bf16x8*)(h0s + ((ks * 2 + 0) * 64 + lane) * 8);
        bf16x8 bB = *(const bf16x8*)(h0s + ((ks * 2 + 1) * 64 + lane) * 8);
        __builtin_amdgcn_s_setprio(1);
        #pragma unroll
        for (int ot = 0; ot < 4; ++ot) {
            acc1[ot][0] = MFMA16(a[ot], bA, acc1[ot][0]);
            acc1[ot][1] = MFMA16(a[ot], bB, acc1[ot][1]);
        }
        __builtin_amdgcn_s_setprio(0);
        #pragma unroll
        for (int ot = 0; ot < 4; ++ot)
            a[ot] = na[ot];
    }

    // ---------------- Layer 2 ----------------------------------------------
    // acc1: o = w*64 + ot*16 + 4*l4 + r, m = nt*16 + l15
    float part[2] = {0.f, 0.f};
    #pragma unroll
    for (int ot = 0; ot < 4; ++ot) {
        const int ob = w * 64 + ot * 16 + 4 * l4;
        const f32x4 b1v = *(const f32x4*)(b1 + c * NH1 + ob);
        const f32x4 w2v = *(const f32x4*)(W2 + c * NH1 + ob);
        #pragma unroll
        for (int r = 0; r < 4; ++r) {
            #pragma unroll
            for (int nt = 0; nt < 2; ++nt) {
                float v = acc1[ot][nt][r] + b1v[r];
                v = v > 0.f ? v : 0.f;
                part[nt] += v * w2v[r];
            }
        }
    }
    #pragma unroll
    for (int nt = 0; nt < 2; ++nt) {
        part[nt] += __shfl_xor(part[nt], 16, 64);
        part[nt] += __shfl_xor(part[nt], 32, 64);
    }
    if (l4 == 0) {
        #pragma unroll
        for (int nt = 0; nt < 2; ++nt)
            red[w][nt * 16 + l15] = part[nt];
    }
    __syncthreads();

    if (tid < BTM) {
        float s = 0.f;
        #pragma unroll
        for (int ww = 0; ww < 4; ++ww) s += red[ww][tid];
        s += b2[c];
        out[(size_t)(row0 + tid) * CNUM + c] = s;
    }
}

// ---------------------------------------------------------------------------
// Fallback (fp32 loads, no workspace) in case ws_size < WS_NEED. BT=64 geom.
// ---------------------------------------------------------------------------
__device__ __forceinline__ bf16x8 ld_cvt8(const float* __restrict__ p) {
    f32x8 v = *(const f32x8*)p;
    bf16x8 r;
    #pragma unroll
    for (int i = 0; i < 8; ++i) r[i] = (__bf16)v[i];
    return r;
}

#define P0 (NH0 + 8)

__global__ __launch_bounds__(NTHREADS, 4)
void confounder_fused(const float* __restrict__ x,
                      const float* __restrict__ W0,
                      const float* __restrict__ b0,
                      const float* __restrict__ W1,
                      const float* __restrict__ b1,
                      const float* __restrict__ W2,
                      const float* __restrict__ b2,
                      float* __restrict__ out) {
    __shared__ __align__(16) __bf16 h0s[BT * P0];
    __shared__ float red[8][BT];

    const int c    = blockIdx.x & 7;
    const int mb   = blockIdx.x >> 3;
    const int row0 = mb * BT;
    const int tid  = threadIdx.x;
    const int w    = tid >> 6;
    const int lane = tid & 63;
    const int l15  = lane & 15;
    const int l4   = lane >> 4;

    f32x4 acc0[4][4];
    #pragma unroll
    for (int mt = 0; mt < 4; ++mt)
        #pragma unroll
        for (int nt = 0; nt < 4; ++nt)
            acc0[mt][nt] = (f32x4){0.f, 0.f, 0.f, 0.f};

    const float* xb  = x  + (size_t)(row0 + l15) * DIN + 8 * l4;
    const float* w0b = W0 + ((size_t)c * NH0 + w * 64 + l15) * DIN + 8 * l4;

    #pragma unroll
    for (int ks = 0; ks < DIN / 32; ++ks) {
        bf16x8 a[4];
        #pragma unroll
        for (int mt = 0; mt < 4; ++mt)
            a[mt] = ld_cvt8(xb + mt * 16 * DIN + ks * 32);
        #pragma unroll
        for (int nt = 0; nt < 4; ++nt) {
            bf16x8 bf = ld_cvt8(w0b + nt * 16 * DIN + ks * 32);
            #pragma unroll
            for (int mt = 0; mt < 4; ++mt)
                acc0[mt][nt] = __builtin_amdgcn_mfma_f32_16x16x32_bf16(a[mt], bf, acc0[mt][nt], 0, 0, 0);
        }
    }
    #pragma unroll
    for (int nt = 0; nt < 4; ++nt) {
        const int n    = (w * 4 + nt) * 16 + l15;
        const float bv = b0[c * NH0 + n];
        #pragma unroll
        for (int mt = 0; mt < 4; ++mt)
            #pragma unroll
            for (int r = 0; r < 4; ++r) {
                float v = acc0[mt][nt][r] + bv;
                v = v > 0.f ? v : 0.f;
                h0s[(mt * 16 + l4 * 4 + r) * P0 + n] = (__bf16)v;
            }
    }
    __syncthreads();

    f32x4 acc1[2][4];
    #pragma unroll
    for (int ot = 0; ot < 2; ++ot)
        #pragma unroll
        for (int nt = 0; nt < 4; ++nt)
            acc1[ot][nt] = (f32x4){0.f, 0.f, 0.f, 0.f};

    const float* w1b = W1 + ((size_t)c * NH1 + w * 32 + l15) * NH0 + 8 * l4;

    #pragma unroll
    for (int ks = 0; ks < NH0 / 32; ++ks) {
        bf16x8 a[2];
        #pragma unroll
        for (int ot = 0; ot < 2; ++ot)
            a[ot] = ld_cvt8(w1b + ot * 16 * NH0 + ks * 32);
        #pragma unroll
        for (int nt = 0; nt < 4; ++nt) {
            bf16x8 bf = *(const bf16x8*)(&h0s[(nt * 16 + l15) * P0 + ks * 32 + 8 * l4]);
            #pragma unroll
            for (int ot = 0; ot < 2; ++ot)
                acc1[ot][nt] = __builtin_amdgcn_mfma_f32_16x16x32_bf16(a[ot], bf, acc1[ot][nt], 0, 0, 0);
        }
    }

    float part[4] = {0.f, 0.f, 0.f, 0.f};
    #pragma unroll
    for (int ot = 0; ot < 2; ++ot)
        #pragma unroll
        for (int r = 0; r < 4; ++r) {
            const int o     = (2 * w + ot) * 16 + l4 * 4 + r;
            const float b1v = b1[c * NH1 + o];
            const float w2v = W2[c * NH1 + o];
            #pragma unroll
            for (int nt = 0; nt < 4; ++nt) {
                float v = acc1[ot][nt][r] + b1v;
                v = v > 0.f ? v : 0.f;
                part[nt] += v * w2v;
            }
        }
    #pragma unroll
    for (int nt = 0; nt < 4; ++nt) {
        part[nt] += __shfl_xor(part[nt], 16, 64);
        part[nt] += __shfl_xor(part[nt], 32, 64);
    }
    if (l4 == 0) {
        #pragma unroll
        for (int nt = 0; nt < 4; ++nt)
            red[w][nt * 16 + l15] = part[nt];
    }
    __syncthreads();

    if (tid < BT) {
        float s = 0.f;
        #pragma unroll
        for (int ww = 0; ww < 8; ++ww) s += red[ww][tid];
        s += b2[c];
        out[(size_t)(row0 + tid) * CNUM + c] = s;
    }
}

extern "C" void kernel_launch(void* const* d_in, const int* in_sizes, int n_in,
                              void* d_out, int out_size, void* d_ws, size_t ws_size,
                              hipStream_t stream) {
    const float* x  = (const float*)d_in[0];
    const float* W0 = (const float*)d_in[1];
    const float* b0 = (const float*)d_in[2];
    const float* W1 = (const float*)d_in[3];
    const float* b1 = (const float*)d_in[4];
    const float* W2 = (const float*)d_in[5];
    const float* b2 = (const float*)d_in[6];
    float* out = (float*)d_out;

    if (ws_size >= WS_NEED) {
        __bf16* ws = (__bf16*)d_ws;
        cvt_bf16<<<dim3((X_ELEMS + W0_ELEMS + W1_ELEMS) / 8 / 256), dim3(256), 0, stream>>>(x, W0, W1, ws);
        confounder_main<<<dim3((BATCH / BTM) * CNUM), dim3(NTMAIN), 0, stream>>>(ws, b0, b1, W2, b2, out);
    } else {
        confounder_fused<<<dim3((BATCH / BT) * CNUM), dim3(NTHREADS), 0, stream>>>(x, W0, b0, W1, b1, W2, b2, out);
    }
}

// Round 9
// 223.394 us; speedup vs baseline: 1.4336x; 1.4336x over previous
//
#include <hip/hip_runtime.h>

// Problem constants (from reference)
#define BATCH 16384
#define CNUM  8
#define DIN   256
#define NH0   512
#define NH1   256

#define BT       64            // batch rows per block
#define NTHREADS 512           // 8 waves

#define X_ELEMS  (BATCH * DIN)        // 4194304
#define W0_ELEMS (CNUM * NH0 * DIN)   // 1048576
#define W1_ELEMS (CNUM * NH1 * NH0)   // 1048576
#define WS_NEED  ((size_t)(X_ELEMS + W0_ELEMS + W1_ELEMS) * 2)  // 12.6 MB bf16

typedef __bf16 bf16x8 __attribute__((ext_vector_type(8)));
typedef __bf16 bf16x4 __attribute__((ext_vector_type(4)));
typedef float  f32x4  __attribute__((ext_vector_type(4)));
typedef float  f32x8  __attribute__((ext_vector_type(8)));

#define MFMA16(a, b, c) __builtin_amdgcn_mfma_f32_16x16x32_bf16((a), (b), (c), 0, 0, 0)
#define SBAR()  __builtin_amdgcn_s_barrier()
#define FENCE() asm volatile("" ::: "memory")
#define WAITV(n) asm volatile("s_waitcnt vmcnt(" #n ")" ::: "memory")
#define WAITLGKM0() asm volatile("s_waitcnt lgkmcnt(0)" ::: "memory")

// Async DMA: global -> LDS, 16 B per lane, dest = wave-uniform base + lane*16.
__device__ __forceinline__ void async16(const __bf16* g, __bf16* l) {
    __builtin_amdgcn_global_load_lds(
        (const __attribute__((address_space(1))) unsigned int*)g,
        (__attribute__((address_space(3))) unsigned int*)l, 16, 0, 0);
}

// ---------------------------------------------------------------------------
// Prep: fp32 -> bf16 for x, W0, W1 into ws.  786432 chunks x 8 elems.
// ---------------------------------------------------------------------------
__global__ __launch_bounds__(256)
void cvt_bf16(const float* __restrict__ x, const float* __restrict__ W0,
              const float* __restrict__ W1, __bf16* __restrict__ ws) {
    const int i = blockIdx.x * 256 + threadIdx.x;   // chunk of 8 elems
    const float* src;
    __bf16* dst;
    int off;
    if (i < X_ELEMS / 8)                 { src = x;  dst = ws;                        off = i * 8; }
    else if (i < (X_ELEMS + W0_ELEMS)/8) { src = W0; dst = ws + X_ELEMS;             off = (i - X_ELEMS/8) * 8; }
    else                                 { src = W1; dst = ws + X_ELEMS + W0_ELEMS;  off = (i - (X_ELEMS + W0_ELEMS)/8) * 8; }
    f32x8 v = *(const f32x8*)(src + off);
    bf16x8 r;
    #pragma unroll
    for (int j = 0; j < 8; ++j) r[j] = (__bf16)v[j];
    *(bf16x8*)(dst + off) = r;
}

// ---------------------------------------------------------------------------
// Main fused kernel: DMA-fed double-buffered pipeline (T3/T4).
// grid = (BATCH/BT)*CNUM = 2048; c = blockIdx&7 (XCD round-robin).
//
// All LDS tiles use the verified 1-KB granule format: granule = 16 rows x
// 32 k; lane l holds (row l&15, k-slot l>>4, 8 elems = 16 B) at byte l*16
// -> every ds_read_b128 is lane-contiguous (conflict-free), and the DMA
// dest (base + lane*16) writes exactly this layout via a per-lane
// pre-swizzled global source address.
//
// LDS map (128 KB, elems of bf16):
//   [0,16384)      xs   : x tile, 32 granules                (L0 phase)
//   [16384,32768)  w0a  : W0 chunk double-buffer 0, 32 gran  (L0)
//   [32768,49152)  w0bq : W0 chunk double-buffer 1           (L0)
//   [49152,57344)  w1a  : W1 chunk double-buffer 0, 16 gran
//   [57344,65536)  w1bq : W1 chunk double-buffer 1
//   [0,32768)      h0   : layer-0 output, 64 granules        (L1 phase;
//                         overlays xs+w0a, both dead after L0 ks=7 SBAR)
//   [32768,...)    red  : 2 KB final reduce (overlays w0bq, dead)
//
// vmcnt FIFO discipline (r8 bug fix): ISSUE ORDER == CONSUMPTION ORDER.
//   prologue: x(4), W0c0(4), W0c1(4)        -> WAITV(4) retires x+c0
//   L0 ks:    refill chunk ks+2 (ks<6); at ks==6 issue W1c0(2)+W1c1(2);
//             WAITV(4) retires exactly chunk ks+1 (FIFO = [c(ks+1), 4 more])
//   L1 ks:    WAITV(2) retires exactly W1 chunk ks; refill ks+2 after SBAR.
// Never a full vmcnt drain inside a loop: 2 chunks always in flight.
// ---------------------------------------------------------------------------
__global__ __launch_bounds__(NTHREADS, 2)
void confounder_main(const __bf16* __restrict__ ws,
                     const float* __restrict__ b0,
                     const float* __restrict__ b1,
                     const float* __restrict__ W2,
                     const float* __restrict__ b2,
                     float* __restrict__ out) {
    __shared__ __align__(16) __bf16 lds[65536];   // 128 KB
    __bf16* xs   = lds;
    __bf16* w0a  = lds + 16384;
    __bf16* w0bq = lds + 32768;
    __bf16* w1a  = lds + 49152;
    __bf16* w1bq = lds + 57344;
    __bf16* h0   = lds;                    // L1-phase alias
    float*  red  = (float*)(lds + 32768);  // final-reduce alias

    const __bf16* xbf = ws;
    const __bf16* w0g = ws + X_ELEMS;
    const __bf16* w1g = ws + X_ELEMS + W0_ELEMS;

    const int c    = blockIdx.x & 7;
    const int mb   = blockIdx.x >> 3;
    const int row0 = mb * BT;

    const int tid  = threadIdx.x;
    const int w    = tid >> 6;    // wave 0..7
    const int lane = tid & 63;
    const int l15  = lane & 15;
    const int l4   = lane >> 4;   // 0..3

    // ---- prologue DMA (per-wave FIFO: x:4, W0c0:4, W0c1:4) ----------------
    #pragma unroll
    for (int rd = 0; rd < 4; ++rd) {      // x granules p = rd*8 + w
        const int p = rd * 8 + w;
        async16(xbf + (size_t)(row0 + (p >> 3) * 16 + l15) * DIN + (p & 7) * 32 + l4 * 8,
                xs + p * 512);
    }
    #pragma unroll
    for (int kc = 0; kc < 2; ++kc)
        #pragma unroll
        for (int rd = 0; rd < 4; ++rd) {  // W0 granules q = rd*8 + w (rows q*16..+15)
            const int q = rd * 8 + w;
            async16(w0g + ((size_t)c * NH0 + q * 16 + l15) * DIN + kc * 32 + l4 * 8,
                    (kc ? w0bq : w0a) + q * 512);
        }

    f32x4 acc0[4][4];   // [at][bt]: n = w*64+at*16+..., m = bt*16+...
    #pragma unroll
    for (int at = 0; at < 4; ++at)
        #pragma unroll
        for (int bt = 0; bt < 4; ++bt)
            acc0[at][bt] = (f32x4){0.f, 0.f, 0.f, 0.f};

    // retire x(4)+W0c0(4): FIFO left = [c1(4)]
    WAITV(4); SBAR(); FENCE();

    // ================= Layer 0: 8 k-steps, W0 dbuf =========================
    #pragma unroll
    for (int ks = 0; ks < 8; ++ks) {
        __bf16* wb = (ks & 1) ? w0bq : w0a;
        bf16x8 aw[4], bx[4];
        #pragma unroll
        for (int at = 0; at < 4; ++at)
            aw[at] = *(const bf16x8*)(wb + (4 * w + at) * 512 + lane * 8);
        #pragma unroll
        for (int bt = 0; bt < 4; ++bt)
            bx[bt] = *(const bf16x8*)(xs + (bt * 8 + ks) * 512 + lane * 8);
        __builtin_amdgcn_s_setprio(1);
        #pragma unroll
        for (int at = 0; at < 4; ++at)
            #pragma unroll
            for (int bt = 0; bt < 4; ++bt)
                acc0[at][bt] = MFMA16(aw[at], bx[bt], acc0[at][bt]);
        __builtin_amdgcn_s_setprio(0);
        FENCE(); SBAR(); FENCE();          // all waves done reading wb
        if (ks < 6) {                      // refill wb with chunk ks+2
            const int kc = ks + 2;
            #pragma unroll
            for (int rd = 0; rd < 4; ++rd) {
                const int q = rd * 8 + w;
                async16(w0g + ((size_t)c * NH0 + q * 16 + l15) * DIN + kc * 32 + l4 * 8,
                        wb + q * 512);
            }
        }
        if (ks == 6) {                     // W1 first two chunks enter FIFO LAST
            #pragma unroll
            for (int kc = 0; kc < 2; ++kc)
                #pragma unroll
                for (int rd = 0; rd < 2; ++rd) {
                    const int q = rd * 8 + w;
                    async16(w1g + ((size_t)c * NH1 + q * 16 + l15) * NH0 + kc * 32 + l4 * 8,
                            (kc ? w1bq : w1a) + q * 512);
                }
        }
        if (ks < 7) {                      // retire exactly chunk ks+1
            WAITV(4); SBAR(); FENCE();
        }
    }
    // trailing SBAR of ks=7 guarantees all xs/w0 reads complete -> h0 overlay ok.

    // ---- epilogue: bias+relu+cvt, h0 granule g = (w*2+(at>>1))*4 + bt -----
    #pragma unroll
    for (int at = 0; at < 4; ++at) {
        const int nb = w * 64 + at * 16 + 4 * l4;
        const f32x4 b4 = *(const f32x4*)(b0 + c * NH0 + nb);
        const int sub = ((at & 1) * 2 + (l4 >> 1)) * 128 + l15 * 8 + 4 * (l4 & 1);
        #pragma unroll
        for (int bt = 0; bt < 4; ++bt) {
            const int g = (w * 2 + (at >> 1)) * 4 + bt;
            bf16x4 pk;
            #pragma unroll
            for (int r = 0; r < 4; ++r) {
                float v = acc0[at][bt][r] + b4[r];
                v = v > 0.f ? v : 0.f;
                pk[r] = (__bf16)v;
            }
            *(bf16x4*)(h0 + g * 512 + sub) = pk;
        }
    }
    WAITLGKM0(); FENCE(); SBAR(); FENCE();   // h0 complete everywhere

    // ================= Layer 1: 16 k-steps, W1 dbuf ========================
    // FIFO entering L1: [W1c0(2), W1c1(2)]
    f32x4 acc1[2][4];   // [ot][bt]: o = (2w+ot)*16+..., m = bt*16+...
    #pragma unroll
    for (int ot = 0; ot < 2; ++ot)
        #pragma unroll
        for (int bt = 0; bt < 4; ++bt)
            acc1[ot][bt] = (f32x4){0.f, 0.f, 0.f, 0.f};

    #pragma unroll
    for (int ks = 0; ks < 16; ++ks) {
        if (ks == 15) { WAITV(0); } else { WAITV(2); }   // retire exactly chunk ks
        SBAR(); FENCE();
        __bf16* wb = (ks & 1) ? w1bq : w1a;
        bf16x8 a2[2], bh[4];
        #pragma unroll
        for (int ot = 0; ot < 2; ++ot)
            a2[ot] = *(const bf16x8*)(wb + (2 * w + ot) * 512 + lane * 8);
        #pragma unroll
        for (int bt = 0; bt < 4; ++bt)
            bh[bt] = *(const bf16x8*)(h0 + (ks * 4 + bt) * 512 + lane * 8);
        __builtin_amdgcn_s_setprio(1);
        #pragma unroll
        for (int ot = 0; ot < 2; ++ot)
            #pragma unroll
            for (int bt = 0; bt < 4; ++bt)
                acc1[ot][bt] = MFMA16(a2[ot], bh[bt], acc1[ot][bt]);
        __builtin_amdgcn_s_setprio(0);
        if (ks < 14) {
            FENCE(); SBAR(); FENCE();      // all waves done reading wb
            const int kc = ks + 2;
            #pragma unroll
            for (int rd = 0; rd < 2; ++rd) {
                const int q = rd * 8 + w;
                async16(w1g + ((size_t)c * NH1 + q * 16 + l15) * NH0 + kc * 32 + l4 * 8,
                        wb + q * 512);
            }
        }
    }

    // ================= Layer 2 =============================================
    // acc1: o = (2w+ot)*16 + 4*l4 + r, m = bt*16 + l15
    float part[4] = {0.f, 0.f, 0.f, 0.f};
    #pragma unroll
    for (int ot = 0; ot < 2; ++ot) {
        const int ob = (2 * w + ot) * 16 + 4 * l4;
        const f32x4 b1v = *(const f32x4*)(b1 + c * NH1 + ob);
        const f32x4 w2v = *(const f32x4*)(W2 + c * NH1 + ob);
        #pragma unroll
        for (int r = 0; r < 4; ++r) {
            #pragma unroll
            for (int bt = 0; bt < 4; ++bt) {
                float v = acc1[ot][bt][r] + b1v[r];
                v = v > 0.f ? v : 0.f;
                part[bt] += v * w2v[r];
            }
        }
    }
    #pragma unroll
    for (int bt = 0; bt < 4; ++bt) {
        part[bt] += __shfl_xor(part[bt], 16, 64);
        part[bt] += __shfl_xor(part[bt], 32, 64);
    }
    if (l4 == 0) {
        #pragma unroll
        for (int bt = 0; bt < 4; ++bt)
            red[w * 64 + bt * 16 + l15] = part[bt];
    }
    __syncthreads();

    if (tid < BT) {
        float s = 0.f;
        #pragma unroll
        for (int ww = 0; ww < 8; ++ww) s += red[ww * 64 + tid];
        s += b2[c];
        out[(size_t)(row0 + tid) * CNUM + c] = s;
    }
}

// ---------------------------------------------------------------------------
// Fallback (fp32 loads, no workspace) in case ws_size < WS_NEED. BT=64 geom.
// ---------------------------------------------------------------------------
__device__ __forceinline__ bf16x8 ld_cvt8(const float* __restrict__ p) {
    f32x8 v = *(const f32x8*)p;
    bf16x8 r;
    #pragma unroll
    for (int i = 0; i < 8; ++i) r[i] = (__bf16)v[i];
    return r;
}

#define P0 (NH0 + 8)

__global__ __launch_bounds__(NTHREADS, 4)
void confounder_fused(const float* __restrict__ x,
                      const float* __restrict__ W0,
                      const float* __restrict__ b0,
                      const float* __restrict__ W1,
                      const float* __restrict__ b1,
                      const float* __restrict__ W2,
                      const float* __restrict__ b2,
                      float* __restrict__ out) {
    __shared__ __align__(16) __bf16 h0s[BT * P0];
    __shared__ float red[8][BT];

    const int c    = blockIdx.x & 7;
    const int mb   = blockIdx.x >> 3;
    const int row0 = mb * BT;
    const int tid  = threadIdx.x;
    const int w    = tid >> 6;
    const int lane = tid & 63;
    const int l15  = lane & 15;
    const int l4   = lane >> 4;

    f32x4 acc0[4][4];
    #pragma unroll
    for (int mt = 0; mt < 4; ++mt)
        #pragma unroll
        for (int nt = 0; nt < 4; ++nt)
            acc0[mt][nt] = (f32x4){0.f, 0.f, 0.f, 0.f};

    const float* xb  = x  + (size_t)(row0 + l15) * DIN + 8 * l4;
    const float* w0b = W0 + ((size_t)c * NH0 + w * 64 + l15) * DIN + 8 * l4;

    #pragma unroll
    for (int ks = 0; ks < DIN / 32; ++ks) {
        bf16x8 a[4];
        #pragma unroll
        for (int mt = 0; mt < 4; ++mt)
            a[mt] = ld_cvt8(xb + mt * 16 * DIN + ks * 32);
        #pragma unroll
        for (int nt = 0; nt < 4; ++nt) {
            bf16x8 bf = ld_cvt8(w0b + nt * 16 * DIN + ks * 32);
            #pragma unroll
            for (int mt = 0; mt < 4; ++mt)
                acc0[mt][nt] = __builtin_amdgcn_mfma_f32_16x16x32_bf16(a[mt], bf, acc0[mt][nt], 0, 0, 0);
        }
    }
    #pragma unroll
    for (int nt = 0; nt < 4; ++nt) {
        const int n    = (w * 4 + nt) * 16 + l15;
        const float bv = b0[c * NH0 + n];
        #pragma unroll
        for (int mt = 0; mt < 4; ++mt)
            #pragma unroll
            for (int r = 0; r < 4; ++r) {
                float v = acc0[mt][nt][r] + bv;
                v = v > 0.f ? v : 0.f;
                h0s[(mt * 16 + l4 * 4 + r) * P0 + n] = (__bf16)v;
            }
    }
    __syncthreads();

    f32x4 acc1[2][4];
    #pragma unroll
    for (int ot = 0; ot < 2; ++ot)
        #pragma unroll
        for (int nt = 0; nt < 4; ++nt)
            acc1[ot][nt] = (f32x4){0.f, 0.f, 0.f, 0.f};

    const float* w1b = W1 + ((size_t)c * NH1 + w * 32 + l15) * NH0 + 8 * l4;

    #pragma unroll
    for (int ks = 0; ks < NH0 / 32; ++ks) {
        bf16x8 a[2];
        #pragma unroll
        for (int ot = 0; ot < 2; ++ot)
            a[ot] = ld_cvt8(w1b + ot * 16 * NH0 + ks * 32);
        #pragma unroll
        for (int nt = 0; nt < 4; ++nt) {
            bf16x8 bf = *(const bf16x8*)(&h0s[(nt * 16 + l15) * P0 + ks * 32 + 8 * l4]);
            #pragma unroll
            for (int ot = 0; ot < 2; ++ot)
                acc1[ot][nt] = __builtin_amdgcn_mfma_f32_16x16x32_bf16(a[ot], bf, acc1[ot][nt], 0, 0, 0);
        }
    }

    float part[4] = {0.f, 0.f, 0.f, 0.f};
    #pragma unroll
    for (int ot = 0; ot < 2; ++ot)
        #pragma unroll
        for (int r = 0; r < 4; ++r) {
            const int o     = (2 * w + ot) * 16 + l4 * 4 + r;
            const float b1v = b1[c * NH1 + o];
            const float w2v = W2[c * NH1 + o];
            #pragma unroll
            for (int nt = 0; nt < 4; ++nt) {
                float v = acc1[ot][nt][r] + b1v;
                v = v > 0.f ? v : 0.f;
                part[nt] += v * w2v;
            }
        }
    #pragma unroll
    for (int nt = 0; nt < 4; ++nt) {
        part[nt] += __shfl_xor(part[nt], 16, 64);
        part[nt] += __shfl_xor(part[nt], 32, 64);
    }
    if (l4 == 0) {
        #pragma unroll
        for (int nt = 0; nt < 4; ++nt)
            red[w][nt * 16 + l15] = part[nt];
    }
    __syncthreads();

    if (tid < BT) {
        float s = 0.f;
        #pragma unroll
        for (int ww = 0; ww < 8; ++ww) s += red[ww][tid];
        s += b2[c];
        out[(size_t)(row0 + tid) * CNUM + c] = s;
    }
}

extern "C" void kernel_launch(void* const* d_in, const int* in_sizes, int n_in,
                              void* d_out, int out_size, void* d_ws, size_t ws_size,
                              hipStream_t stream) {
    const float* x  = (const float*)d_in[0];
    const float* W0 = (const float*)d_in[1];
    const float* b0 = (const float*)d_in[2];
    const float* W1 = (const float*)d_in[3];
    const float* b1 = (const float*)d_in[4];
    const float* W2 = (const float*)d_in[5];
    const float* b2 = (const float*)d_in[6];
    float* out = (float*)d_out;

    if (ws_size >= WS_NEED) {
        __bf16* ws = (__bf16*)d_ws;
        cvt_bf16<<<dim3((X_ELEMS + W0_ELEMS + W1_ELEMS) / 8 / 256), dim3(256), 0, stream>>>(x, W0, W1, ws);
        confounder_main<<<dim3((BATCH / BT) * CNUM), dim3(NTHREADS), 0, stream>>>(ws, b0, b1, W2, b2, out);
    } else {
        confounder_fused<<<dim3((BATCH / BT) * CNUM), dim3(NTHREADS), 0, stream>>>(x, W0, b0, W1, b1, W2, b2, out);
    }
}

// Round 10
// 158.777 us; speedup vs baseline: 2.0171x; 1.4070x over previous
//
#include <hip/hip_runtime.h>

// Problem constants (from reference)
#define BATCH 16384
#define CNUM  8
#define DIN   256
#define NH0   512
#define NH1   256

#define BT       64            // batch rows per block (fallback kernel)
#define BTM      128           // batch rows per block (main kernel)
#define NTMAIN   1024          // 16 waves
#define NTHREADS 512           // fallback

#define X_ELEMS  (BATCH * DIN)        // 4194304
#define W0_ELEMS (CNUM * NH0 * DIN)   // 1048576
#define W1_ELEMS (CNUM * NH1 * NH0)   // 1048576
#define WS_NEED  ((size_t)(X_ELEMS + W0_ELEMS + W1_ELEMS) * 2)  // 12.6 MB bf16

typedef __bf16 bf16x8 __attribute__((ext_vector_type(8)));
typedef __bf16 bf16x4 __attribute__((ext_vector_type(4)));
typedef float  f32x4  __attribute__((ext_vector_type(4)));
typedef float  f32x8  __attribute__((ext_vector_type(8)));

#define MFMA16(a, b, c) __builtin_amdgcn_mfma_f32_16x16x32_bf16((a), (b), (c), 0, 0, 0)

// ---------------------------------------------------------------------------
// Prep: fp32 -> bf16 for x, W0, W1 into ws.  786432 chunks x 8 elems.
// ---------------------------------------------------------------------------
__global__ __launch_bounds__(256)
void cvt_bf16(const float* __restrict__ x, const float* __restrict__ W0,
              const float* __restrict__ W1, __bf16* __restrict__ ws) {
    const int i = blockIdx.x * 256 + threadIdx.x;   // chunk of 8 elems
    const float* src;
    __bf16* dst;
    int off;
    if (i < X_ELEMS / 8)                 { src = x;  dst = ws;                        off = i * 8; }
    else if (i < (X_ELEMS + W0_ELEMS)/8) { src = W0; dst = ws + X_ELEMS;             off = (i - X_ELEMS/8) * 8; }
    else                                 { src = W1; dst = ws + X_ELEMS + W0_ELEMS;  off = (i - (X_ELEMS + W0_ELEMS)/8) * 8; }
    f32x8 v = *(const f32x8*)(src + off);
    bf16x8 r;
    #pragma unroll
    for (int j = 0; j < 8; ++j) r[j] = (__bf16)v[j];
    *(bf16x8*)(dst + off) = r;
}

// ---------------------------------------------------------------------------
// Main fused kernel: BT=128, 16 waves, 4 barriers TOTAL per block.
// grid = (BATCH/BTM)*CNUM = 1024; c = blockIdx&7 (XCD round-robin).
//
// Rounds 0-9 triangulated the plateau: work-per-barrier and work-per-
// weight-byte at BT=64 are too small; all micro levers (layout, occupancy,
// pipelining, DMA) land ~140 us. This kernel doubles the tile:
//   - weight L2 traffic halves (1024 blocks x 544 KB),
//   - L0 runs barrier-FREE (W0 streams through regs, r4-style compiler
//     scheduling -- the best-measured pattern), 16 MFMA + 8 ds_read/k-step,
//   - L1 runs barrier-free too (8 MFMA + 8 ds_read + 1 global load/k-step).
//
// LDS: h0s = 128 granules x 1 KB (frag-major: granule g = bt*16 + kw holds
// m-tile bt, k-chunk kw; lane l's 16 B = row l&15, k-slot l>>4 -> every
// ds_read_b128 lane-contiguous, conflict-free). xs (x tile, 64 granules,
// g = mt*8 + kc) aliases granules 0..63 during L0; h0 epilogue overwrites
// after one barrier. red[16][128] f32 separate (8 KB). Total 136 KB.
// ---------------------------------------------------------------------------
__global__ __launch_bounds__(NTMAIN, 4)
void confounder_main(const __bf16* __restrict__ ws,
                     const float* __restrict__ b0,
                     const float* __restrict__ b1,
                     const float* __restrict__ W2,
                     const float* __restrict__ b2,
                     float* __restrict__ out) {
    __shared__ __align__(16) __bf16 h0s[BTM * NH0];  // 131072 B
    __shared__ float red[16][BTM];                   // 8192 B
    __bf16* xs = h0s;                                // granules 0..63 alias

    const __bf16* xbf = ws;
    const __bf16* w0b = ws + X_ELEMS;
    const __bf16* w1b = ws + X_ELEMS + W0_ELEMS;

    const int c    = blockIdx.x & 7;
    const int mb   = blockIdx.x >> 3;
    const int row0 = mb * BTM;

    const int tid  = threadIdx.x;
    const int w    = tid >> 6;    // wave 0..15
    const int lane = tid & 63;
    const int l15  = lane & 15;
    const int l4   = lane >> 4;   // 0..3

    // ---- stage x tile (128 m x 256 k) into granules 0..63, frag-major -----
    // granule p = mt*8 + kc; lane: row mt*16+l15, cols kc*32 + 8*l4 .. +7
    #pragma unroll
    for (int q = 0; q < 4; ++q) {
        const int p  = w * 4 + q;             // 0..63
        const int mt = p >> 3, kc = p & 7;
        bf16x8 v = *(const bf16x8*)(xbf + (size_t)(row0 + mt * 16 + l15) * DIN + kc * 32 + 8 * l4);
        *(bf16x8*)(xs + (p * 64 + lane) * 8) = v;
    }

    // W0 rows: wave w covers n = w*32 + at*16 + l15 (at 0..1)
    const __bf16* w0r = w0b + ((size_t)c * NH0 + w * 32 + l15) * DIN + 8 * l4;
    // W1 rows: wave w covers o = w*16 + l15
    const __bf16* w1r = w1b + ((size_t)c * NH1 + w * 16 + l15) * NH0 + 8 * l4;

    // prefetch L0 ks=0 fragments across the barrier
    bf16x8 a0 = *(const bf16x8*)(w0r);
    bf16x8 a1 = *(const bf16x8*)(w0r + 16 * DIN);
    __syncthreads();                                   // [barrier 1] xs ready

    // ================= Layer 0: n-slice 32, m = 128, K = 256 ===============
    f32x4 acc0[2][8];   // [at][bt] = 64 VGPRs
    #pragma unroll
    for (int at = 0; at < 2; ++at)
        #pragma unroll
        for (int bt = 0; bt < 8; ++bt)
            acc0[at][bt] = (f32x4){0.f, 0.f, 0.f, 0.f};

    #pragma unroll
    for (int ks = 0; ks < 8; ++ks) {
        bf16x8 na0 = a0, na1 = a1;
        if (ks < 7) {
            na0 = *(const bf16x8*)(w0r + (ks + 1) * 32);
            na1 = *(const bf16x8*)(w0r + 16 * DIN + (ks + 1) * 32);
        }
        __builtin_amdgcn_s_setprio(1);
        #pragma unroll
        for (int bt = 0; bt < 8; ++bt) {
            bf16x8 bx = *(const bf16x8*)(xs + ((bt * 8 + ks) * 64 + lane) * 8);
            acc0[0][bt] = MFMA16(a0, bx, acc0[0][bt]);
            acc0[1][bt] = MFMA16(a1, bx, acc0[1][bt]);
        }
        __builtin_amdgcn_s_setprio(0);
        a0 = na0; a1 = na1;
    }

    // prefetch W1 ks=0 (rides through barrier + epilogue)
    bf16x8 q0 = *(const bf16x8*)(w1r);

    __syncthreads();                                   // [barrier 2] xs reads done

    // ---- epilogue: bias+relu+cvt -> h0 granule g = bt*16 + w --------------
    // n = w*32 + at*16 + 4*l4 + r, m = bt*16 + l15
    #pragma unroll
    for (int at = 0; at < 2; ++at) {
        const int nb = w * 32 + at * 16 + 4 * l4;
        const f32x4 b4 = *(const f32x4*)(b0 + c * NH0 + nb);
        const int sub = (at * 2 + (l4 >> 1)) * 128 + l15 * 8 + 4 * (l4 & 1);
        #pragma unroll
        for (int bt = 0; bt < 8; ++bt) {
            const int g = bt * 16 + w;
            bf16x4 pk;
            #pragma unroll
            for (int r = 0; r < 4; ++r) {
                float v = acc0[at][bt][r] + b4[r];
                v = v > 0.f ? v : 0.f;
                pk[r] = (__bf16)v;
            }
            *(bf16x4*)(&h0s[g * 512 + sub]) = pk;
        }
    }
    __syncthreads();                                   // [barrier 3] h0 complete

    // ================= Layer 1: o-slice 16, m = 128, K = 512 ===============
    // h0 granule for (ks, bt): g = bt*16 + ks
    f32x4 acc1[8];   // [bt] = 32 VGPRs
    #pragma unroll
    for (int bt = 0; bt < 8; ++bt)
        acc1[bt] = (f32x4){0.f, 0.f, 0.f, 0.f};

    bf16x8 a = q0;
    #pragma unroll
    for (int ks = 0; ks < 16; ++ks) {
        bf16x8 na = a;
        if (ks < 15) na = *(const bf16x8*)(w1r + (ks + 1) * 32);
        __builtin_amdgcn_s_setprio(1);
        #pragma unroll
        for (int bt = 0; bt < 8; ++bt) {
            bf16x8 bh = *(const bf16x8*)(&h0s[((bt * 16 + ks) * 64 + lane) * 8]);
            acc1[bt] = MFMA16(a, bh, acc1[bt]);
        }
        __builtin_amdgcn_s_setprio(0);
        a = na;
    }

    // ================= Layer 2 =============================================
    // acc1[bt]: o = w*16 + 4*l4 + r, m = bt*16 + l15
    float part[8] = {0.f, 0.f, 0.f, 0.f, 0.f, 0.f, 0.f, 0.f};
    {
        const int ob = w * 16 + 4 * l4;
        const f32x4 b1v = *(const f32x4*)(b1 + c * NH1 + ob);
        const f32x4 w2v = *(const f32x4*)(W2 + c * NH1 + ob);
        #pragma unroll
        for (int r = 0; r < 4; ++r) {
            #pragma unroll
            for (int bt = 0; bt < 8; ++bt) {
                float v = acc1[bt][r] + b1v[r];
                v = v > 0.f ? v : 0.f;
                part[bt] += v * w2v[r];
            }
        }
    }
    #pragma unroll
    for (int bt = 0; bt < 8; ++bt) {
        part[bt] += __shfl_xor(part[bt], 16, 64);
        part[bt] += __shfl_xor(part[bt], 32, 64);
    }
    if (l4 == 0) {
        #pragma unroll
        for (int bt = 0; bt < 8; ++bt)
            red[w][bt * 16 + l15] = part[bt];
    }
    __syncthreads();                                   // [barrier 4]

    if (tid < BTM) {
        float s = 0.f;
        #pragma unroll
        for (int ww = 0; ww < 16; ++ww) s += red[ww][tid];
        s += b2[c];
        out[(size_t)(row0 + tid) * CNUM + c] = s;
    }
}

// ---------------------------------------------------------------------------
// Fallback (fp32 loads, no workspace) in case ws_size < WS_NEED. BT=64 geom.
// ---------------------------------------------------------------------------
__device__ __forceinline__ bf16x8 ld_cvt8(const float* __restrict__ p) {
    f32x8 v = *(const f32x8*)p;
    bf16x8 r;
    #pragma unroll
    for (int i = 0; i < 8; ++i) r[i] = (__bf16)v[i];
    return r;
}

#define P0 (NH0 + 8)

__global__ __launch_bounds__(NTHREADS, 4)
void confounder_fused(const float* __restrict__ x,
                      const float* __restrict__ W0,
                      const float* __restrict__ b0,
                      const float* __restrict__ W1,
                      const float* __restrict__ b1,
                      const float* __restrict__ W2,
                      const float* __restrict__ b2,
                      float* __restrict__ out) {
    __shared__ __align__(16) __bf16 h0s[BT * P0];
    __shared__ float red[8][BT];

    const int c    = blockIdx.x & 7;
    const int mb   = blockIdx.x >> 3;
    const int row0 = mb * BT;
    const int tid  = threadIdx.x;
    const int w    = tid >> 6;
    const int lane = tid & 63;
    const int l15  = lane & 15;
    const int l4   = lane >> 4;

    f32x4 acc0[4][4];
    #pragma unroll
    for (int mt = 0; mt < 4; ++mt)
        #pragma unroll
        for (int nt = 0; nt < 4; ++nt)
            acc0[mt][nt] = (f32x4){0.f, 0.f, 0.f, 0.f};

    const float* xb  = x  + (size_t)(row0 + l15) * DIN + 8 * l4;
    const float* w0b = W0 + ((size_t)c * NH0 + w * 64 + l15) * DIN + 8 * l4;

    #pragma unroll
    for (int ks = 0; ks < DIN / 32; ++ks) {
        bf16x8 a[4];
        #pragma unroll
        for (int mt = 0; mt < 4; ++mt)
            a[mt] = ld_cvt8(xb + mt * 16 * DIN + ks * 32);
        #pragma unroll
        for (int nt = 0; nt < 4; ++nt) {
            bf16x8 bf = ld_cvt8(w0b + nt * 16 * DIN + ks * 32);
            #pragma unroll
            for (int mt = 0; mt < 4; ++mt)
                acc0[mt][nt] = __builtin_amdgcn_mfma_f32_16x16x32_bf16(a[mt], bf, acc0[mt][nt], 0, 0, 0);
        }
    }
    #pragma unroll
    for (int nt = 0; nt < 4; ++nt) {
        const int n    = (w * 4 + nt) * 16 + l15;
        const float bv = b0[c * NH0 + n];
        #pragma unroll
        for (int mt = 0; mt < 4; ++mt)
            #pragma unroll
            for (int r = 0; r < 4; ++r) {
                float v = acc0[mt][nt][r] + bv;
                v = v > 0.f ? v : 0.f;
                h0s[(mt * 16 + l4 * 4 + r) * P0 + n] = (__bf16)v;
            }
    }
    __syncthreads();

    f32x4 acc1[2][4];
    #pragma unroll
    for (int ot = 0; ot < 2; ++ot)
        #pragma unroll
        for (int nt = 0; nt < 4; ++nt)
            acc1[ot][nt] = (f32x4){0.f, 0.f, 0.f, 0.f};

    const float* w1b = W1 + ((size_t)c * NH1 + w * 32 + l15) * NH0 + 8 * l4;

    #pragma unroll
    for (int ks = 0; ks < NH0 / 32; ++ks) {
        bf16x8 a[2];
        #pragma unroll
        for (int ot = 0; ot < 2; ++ot)
            a[ot] = ld_cvt8(w1b + ot * 16 * NH0 + ks * 32);
        #pragma unroll
        for (int nt = 0; nt < 4; ++nt) {
            bf16x8 bf = *(const bf16x8*)(&h0s[(nt * 16 + l15) * P0 + ks * 32 + 8 * l4]);
            #pragma unroll
            for (int ot = 0; ot < 2; ++ot)
                acc1[ot][nt] = __builtin_amdgcn_mfma_f32_16x16x32_bf16(a[ot], bf, acc1[ot][nt], 0, 0, 0);
        }
    }

    float part[4] = {0.f, 0.f, 0.f, 0.f};
    #pragma unroll
    for (int ot = 0; ot < 2; ++ot)
        #pragma unroll
        for (int r = 0; r < 4; ++r) {
            const int o     = (2 * w + ot) * 16 + l4 * 4 + r;
            const float b1v = b1[c * NH1 + o];
            const float w2v = W2[c * NH1 + o];
            #pragma unroll
            for (int nt = 0; nt < 4; ++nt) {
                float v = acc1[ot][nt][r] + b1v;
                v = v > 0.f ? v : 0.f;
                part[nt] += v * w2v;
            }
        }
    #pragma unroll
    for (int nt = 0; nt < 4; ++nt) {
        part[nt] += __shfl_xor(part[nt], 16, 64);
        part[nt] += __shfl_xor(part[nt], 32, 64);
    }
    if (l4 == 0) {
        #pragma unroll
        for (int nt = 0; nt < 4; ++nt)
            red[w][nt * 16 + l15] = part[nt];
    }
    __syncthreads();

    if (tid < BT) {
        float s = 0.f;
        #pragma unroll
        for (int ww = 0; ww < 8; ++ww) s += red[ww][tid];
        s += b2[c];
        out[(size_t)(row0 + tid) * CNUM + c] = s;
    }
}

extern "C" void kernel_launch(void* const* d_in, const int* in_sizes, int n_in,
                              void* d_out, int out_size, void* d_ws, size_t ws_size,
                              hipStream_t stream) {
    const float* x  = (const float*)d_in[0];
    const float* W0 = (const float*)d_in[1];
    const float* b0 = (const float*)d_in[2];
    const float* W1 = (const float*)d_in[3];
    const float* b1 = (const float*)d_in[4];
    const float* W2 = (const float*)d_in[5];
    const float* b2 = (const float*)d_in[6];
    float* out = (float*)d_out;

    if (ws_size >= WS_NEED) {
        __bf16* ws = (__bf16*)d_ws;
        cvt_bf16<<<dim3((X_ELEMS + W0_ELEMS + W1_ELEMS) / 8 / 256), dim3(256), 0, stream>>>(x, W0, W1, ws);
        confounder_main<<<dim3((BATCH / BTM) * CNUM), dim3(NTMAIN), 0, stream>>>(ws, b0, b1, W2, b2, out);
    } else {
        confounder_fused<<<dim3((BATCH / BT) * CNUM), dim3(NTHREADS), 0, stream>>>(x, W0, b0, W1, b1, W2, b2, out);
    }
}